// Round 13
// baseline (242.520 us; speedup 1.0000x reference)
//
#include <hip/hip_runtime.h>

#define N 8192
#define D 256
#define NB 64                        // number of 128-row blocks
#define NTILES (NB * (NB + 1) / 2)   // 2080 upper-triangle tiles
#define MAGIC 0x13579BDFu

typedef float f32x4 __attribute__((ext_vector_type(4)));
typedef long long i64;

// async global->LDS, 16 bytes/lane; LDS dest is wave-uniform base + lane*16
__device__ __forceinline__ void gload16(const void* g, void* lds) {
    __builtin_amdgcn_global_load_lds(
        (const __attribute__((address_space(1))) void*)g,
        (__attribute__((address_space(3))) void*)lds, 16, 0, 0);
}

// u32 key: [31:13] = float bits of val (val>=0, 10-bit mantissa kept),
// [12:0] = 0x1FFF - idx. u32 max == (max val, tie -> min idx) up to
// truncation; finalize recomputes distances exactly in fp32.

// ---------------------------------------------------------------- kernel 0
// prep: fp8 (OCP e4m3) convert + row norms + zero keys + zero out
__global__ __launch_bounds__(256) void prep_kernel(const float* __restrict__ q,
                                                   unsigned char* __restrict__ q8,
                                                   float* __restrict__ sq,
                                                   unsigned* __restrict__ pos_key,
                                                   unsigned* __restrict__ neg_key,
                                                   float* __restrict__ out) {
    const int row = blockIdx.x * 4 + (threadIdx.x >> 6);
    const int lane = threadIdx.x & 63;
    if (threadIdx.x < 8) {
        const int r0 = blockIdx.x * 4 + (threadIdx.x >> 1);
        if (threadIdx.x & 1) neg_key[r0] = 0u; else pos_key[r0] = 0u;
    }
    if (blockIdx.x == 0 && threadIdx.x == 0) out[0] = 0.0f;
    const float4 v = ((const float4*)(q + row * D))[lane];
    int r = 0;
    r = __builtin_amdgcn_cvt_pk_fp8_f32(v.x, v.y, r, false);  // bytes 0,1
    r = __builtin_amdgcn_cvt_pk_fp8_f32(v.z, v.w, r, true);   // bytes 2,3
    ((int*)(q8 + (size_t)row * D))[lane] = r;
    float s = v.x * v.x + v.y * v.y + v.z * v.z + v.w * v.w;
    #pragma unroll
    for (int off = 32; off; off >>= 1) s += __shfl_down(s, off, 64);
    if (lane == 0) sq[row] = s;
}

// ---------------------------------------------------------------- kernel 1
// r10 body (proven fastest) + fused finalize: after the tile epilogue each
// block releases a completion flag; the last 64 blocks (IDs >= NTILES-64,
// << residency capacity -> deadlock-free for any dispatch order) spin on
// all 2080 flags (agent-scope acquire = XCD-coherent), then compute the
// exact fp32 loss for 128 rows each + one atomicAdd into out.
__global__ __launch_bounds__(256, 3) void mine_kernel(
    const unsigned char* __restrict__ q8, const int* __restrict__ tgt,
    const float* __restrict__ sqv, const float* __restrict__ q,
    unsigned* __restrict__ pos_key, unsigned* __restrict__ neg_key,
    unsigned* __restrict__ dflags, float* __restrict__ out)
{
    __shared__ __align__(16) unsigned Msh[2 * 128 * 33];  // merge; front 16KB = staging
    __shared__ float sqI[128], sqJ[128];
    __shared__ int   tgI[128], tgJ[128];
    char* const smem = (char*)Msh;                 // A: [0,8K), B: [8K,16K)

    // triangular tile map: blockIdx.x -> (bi, bj), bi <= bj
    int tt = blockIdx.x, bi = 0;
    while (tt >= NB - bi) { tt -= NB - bi; ++bi; }
    const int bj = bi + tt;
    const int i0 = bi * 128, j0 = bj * 128;
    const bool diag = (bi == bj);

    const int tid = threadIdx.x;
    const int w = tid >> 6, lane = tid & 63;
    const int quad = lane >> 4, lc = lane & 15;
    const int wy = w >> 1, wx = w & 1;

    if (tid < 128) { sqI[tid] = sqv[i0 + tid]; tgI[tid] = tgt[i0 + tid]; }
    else { const int c = tid - 128; sqJ[c] = sqv[j0 + c]; tgJ[c] = tgt[j0 + c]; }
    __syncthreads();  // acc-init reads sqI/sqJ

    // acc init: -(si + sqj)/2  =>  after MFMA chain, acc = -dist/2
    float sqjn[4];
    #pragma unroll
    for (int nt = 0; nt < 4; ++nt) sqjn[nt] = sqJ[wx * 64 + nt * 16 + lc];
    f32x4 acc[4][4];
    #pragma unroll
    for (int mt = 0; mt < 4; ++mt) {
        const f32x4 si4 = *(const f32x4*)&sqI[wy * 64 + mt * 16 + quad * 4];
        #pragma unroll
        for (int nt = 0; nt < 4; ++nt)
            #pragma unroll
            for (int r = 0; r < 4; ++r)
                acc[mt][nt][r] = -0.5f * (si4[r] + sqjn[nt]);
    }

    // K-loop: 4 chunks of K=64 (64 B/row fp8), panel = 512 16B slots
    for (int c = 0; c < D / 64; ++c) {
        const int dkb = c * 64;
        __syncthreads();                 // prev chunk's frag reads done
        #pragma unroll
        for (int it = 0; it < 2; ++it) {
            const int s = it * 256 + tid;         // slot id, 0..511
            const int r = s >> 2, bo = (s & 3) * 16;
            const int lbase = (it * 256 + w * 64) * 16;   // wave-uniform bytes
            gload16(q8 + (size_t)(i0 + r) * D + dkb + bo, smem + lbase);
            if (!diag)
                gload16(q8 + (size_t)(j0 + r) * D + dkb + bo, smem + 8192 + lbase);
        }
        __syncthreads();

        const char* AP = smem;
        const char* BP = diag ? AP : smem + 8192;
        union { int4 v; i64 d[2]; } fb[4], fa;
        #pragma unroll
        for (int t = 0; t < 4; ++t)
            fb[t].v = *(const int4*)(BP + (wx * 64 + t * 16 + lc) * 64 + quad * 16);
        #pragma unroll
        for (int mt = 0; mt < 4; ++mt) {
            fa.v = *(const int4*)(AP + (wy * 64 + mt * 16 + lc) * 64 + quad * 16);
            #pragma unroll
            for (int nt = 0; nt < 4; ++nt) {
                acc[mt][nt] = __builtin_amdgcn_mfma_f32_16x16x32_fp8_fp8(
                    fa.d[0], fb[nt].d[0], acc[mt][nt], 0, 0, 0);
                acc[mt][nt] = __builtin_amdgcn_mfma_f32_16x16x32_fp8_fp8(
                    fa.d[1], fb[nt].d[1], acc[mt][nt], 0, 0, 0);
            }
        }
    }
    __syncthreads();   // all frag reads done — staging LDS reusable as merge

    unsigned* const mpos = Msh;
    unsigned* const mneg = Msh + 128 * 33;

    // ---- epilogue: u32 keys, LDS-merge I-side, shuffle-merge J-side
    int tj[4]; unsigned jc[4], jpk[4], jnk[4];
    #pragma unroll
    for (int nt = 0; nt < 4; ++nt) {
        const int cl = wx * 64 + nt * 16 + lc;
        tj[nt] = tgJ[cl];
        jc[nt] = 0x1FFFu - (unsigned)(j0 + cl);   // I-side idx field (col)
        jpk[nt] = 0u; jnk[nt] = 0u;
    }

    #pragma unroll
    for (int mt = 0; mt < 4; ++mt) {
        const int rbase = wy * 64 + mt * 16 + quad * 4;
        const int4 ti4 = *(const int4*)&tgI[rbase];
        #pragma unroll
        for (int r = 0; r < 4; ++r) {
            const int sr = rbase + r;
            const unsigned rk = 0x1FFFu - (unsigned)(i0 + sr);  // J idx field
            const int ti = ((const int*)&ti4)[r];
            unsigned bpk = 0u, bnk = 0u;
            #pragma unroll
            for (int nt = 0; nt < 4; ++nt) {
                const int cl = wx * 64 + nt * 16 + lc;
                const float dist = fmaxf(-2.0f * acc[mt][nt][r], 0.0f);
                const unsigned db = __float_as_uint(dist) & 0xFFFFE000u;
                const bool same = (ti == tj[nt]);
                const bool dia = diag && (sr == cl);
                const unsigned pb_ = dia ? 0u : (same ? db : 0u);
                const unsigned nb_ = dia ? 0u : (same ? 0u : db);
                bpk = max(bpk, dia ? 0u : (pb_ | jc[nt]));
                bnk = max(bnk, dia ? 0u : (nb_ | jc[nt]));
                jpk[nt] = max(jpk[nt], dia ? 0u : (pb_ | rk));
                jnk[nt] = max(jnk[nt], dia ? 0u : (nb_ | rk));
            }
            mpos[sr * 33 + wx * 16 + lc] = bpk;
            mneg[sr * 33 + wx * 16 + lc] = bnk;
        }
    }
    __syncthreads();

    // I-side owner merge: tid<128 -> pos row tid; tid>=128 -> neg row tid-128
    {
        const int sr = tid & 127;
        const unsigned* m = (tid < 128) ? &mpos[sr * 33] : &mneg[sr * 33];
        unsigned best = 0u;
        #pragma unroll
        for (int k = 0; k < 32; ++k) best = max(best, m[k]);
        unsigned* gk = (tid < 128) ? pos_key : neg_key;
        atomicMax(&gk[i0 + sr], best);
    }

    // J-side: merge 4 quads within wave, then atomic (both wy waves emit)
    if (!diag) {
        #pragma unroll
        for (int nt = 0; nt < 4; ++nt) {
            unsigned pk = jpk[nt], nk = jnk[nt];
            #pragma unroll
            for (int off = 16; off < 64; off <<= 1) {
                pk = max(pk, (unsigned)__shfl_xor((int)pk, off, 64));
                nk = max(nk, (unsigned)__shfl_xor((int)nk, off, 64));
            }
            if (quad == 0) {
                const int gcol = j0 + wx * 64 + nt * 16 + lc;
                atomicMax(&pos_key[gcol], pk);
                atomicMax(&neg_key[gcol], nk);
            }
        }
    }

    // ---- completion flag (release, device/agent scope)
    __threadfence();
    if (tid == 0)
        __hip_atomic_store(&dflags[blockIdx.x], MAGIC,
                           __ATOMIC_RELEASE, __HIP_MEMORY_SCOPE_AGENT);

    // ---- fused finalize: last 64 blocks wait for all tiles, then compute
    // the exact fp32 loss for 128 rows each (identical math to old final_kernel)
    if (blockIdx.x >= NTILES - 64) {
        for (int i = tid; i < NTILES; i += 256)
            while (__hip_atomic_load(&dflags[i], __ATOMIC_ACQUIRE,
                                     __HIP_MEMORY_SCOPE_AGENT) != MAGIC)
                __builtin_amdgcn_s_sleep(2);
        __syncthreads();   // all threads' acquires done

        __shared__ float red[4];
        const int fb = blockIdx.x - (NTILES - 64);
        const int wv = tid >> 6;
        float wsum = 0.0f;
        for (int rr = 0; rr < 32; ++rr) {
            const int row = (fb * 4 + wv) * 32 + rr;
            const int bpi = 0x1FFF - (int)(pos_key[row] & 0x1FFFu);
            const int bni = 0x1FFF - (int)(neg_key[row] & 0x1FFFu);
            const float4 qi = ((const float4*)(q + row * D))[lane];
            const float4 qp = ((const float4*)(q + (size_t)bpi * D))[lane];
            const float4 qn = ((const float4*)(q + (size_t)bni * D))[lane];
            float dx, dp = 0.0f, dn = 0.0f;
            dx = qi.x - qp.x; dp += dx * dx;
            dx = qi.y - qp.y; dp += dx * dx;
            dx = qi.z - qp.z; dp += dx * dx;
            dx = qi.w - qp.w; dp += dx * dx;
            dx = qi.x - qn.x; dn += dx * dx;
            dx = qi.y - qn.y; dn += dx * dx;
            dx = qi.z - qn.z; dn += dx * dx;
            dx = qi.w - qn.w; dn += dx * dx;
            #pragma unroll
            for (int off = 32; off; off >>= 1) {
                dp += __shfl_down(dp, off, 64);
                dn += __shfl_down(dn, off, 64);
            }
            if (lane == 0) wsum += fmaxf(0.0f, (1.0f - dp) + dn);
        }
        if (lane == 0) red[wv] = wsum;
        __syncthreads();
        if (tid == 0)
            atomicAdd(out, (red[0] + red[1] + red[2] + red[3]) * (1.0f / N));
    }
}

// ----------------------------------------------------------------
extern "C" void kernel_launch(void* const* d_in, const int* in_sizes, int n_in,
                              void* d_out, int out_size, void* d_ws, size_t ws_size,
                              hipStream_t stream) {
    const float* q = (const float*)d_in[0];
    const int* tgt = (const int*)d_in[1];
    float* out = (float*)d_out;

    // ws layout (~2.2 MB)
    unsigned* pos_key = (unsigned*)d_ws;              // N
    unsigned* neg_key = pos_key + N;                  // N
    unsigned char* q8 = (unsigned char*)(neg_key + N);// N*D bytes
    float* sqv = (float*)(q8 + (size_t)N * D);        // N
    unsigned* dflags = (unsigned*)(sqv + N);          // NTILES

    prep_kernel<<<dim3(N / 4), dim3(256), 0, stream>>>(q, q8, sqv, pos_key, neg_key, out);
    mine_kernel<<<dim3(NTILES), dim3(256), 0, stream>>>(
        q8, tgt, sqv, q, pos_key, neg_key, dflags, out);
}

// Round 14
// 105.850 us; speedup vs baseline: 2.2912x; 2.2912x over previous
//
#include <hip/hip_runtime.h>

#define N 8192
#define D 256
#define NB 64                        // number of 128-row blocks
#define NTILES (NB * (NB + 1) / 2)   // 2080 upper-triangle tiles

typedef float f32x4 __attribute__((ext_vector_type(4)));
typedef long long i64;

// async global->LDS, 16 bytes/lane; LDS dest is wave-uniform base + lane*16
__device__ __forceinline__ void gload16(const void* g, void* lds) {
    __builtin_amdgcn_global_load_lds(
        (const __attribute__((address_space(1))) void*)g,
        (__attribute__((address_space(3))) void*)lds, 16, 0, 0);
}

// u32 key: [31:13] = float bits of val (val>=0, 10-bit mantissa kept),
// [12:0] = 0x1FFF - idx. u32 max == (max val, tie -> min idx) up to
// truncation; finalize recomputes distances exactly in fp32.

// ---------------------------------------------------------------- kernel 0
// prep: fp8 (OCP e4m3) convert + row norms + zero keys + zero out
__global__ __launch_bounds__(256) void prep_kernel(const float* __restrict__ q,
                                                   unsigned char* __restrict__ q8,
                                                   float* __restrict__ sq,
                                                   unsigned* __restrict__ pos_key,
                                                   unsigned* __restrict__ neg_key,
                                                   float* __restrict__ out) {
    const int row = blockIdx.x * 4 + (threadIdx.x >> 6);
    const int lane = threadIdx.x & 63;
    if (threadIdx.x < 8) {
        const int r0 = blockIdx.x * 4 + (threadIdx.x >> 1);
        if (threadIdx.x & 1) neg_key[r0] = 0u; else pos_key[r0] = 0u;
    }
    if (blockIdx.x == 0 && threadIdx.x == 0) out[0] = 0.0f;
    const float4 v = ((const float4*)(q + row * D))[lane];
    int r = 0;
    r = __builtin_amdgcn_cvt_pk_fp8_f32(v.x, v.y, r, false);  // bytes 0,1
    r = __builtin_amdgcn_cvt_pk_fp8_f32(v.z, v.w, r, true);   // bytes 2,3
    ((int*)(q8 + (size_t)row * D))[lane] = r;
    float s = v.x * v.x + v.y * v.y + v.z * v.z + v.w * v.w;
    #pragma unroll
    for (int off = 32; off; off >>= 1) s += __shfl_down(s, off, 64);
    if (lane == 0) sq[row] = s;
}

// ---------------------------------------------------------------- kernel 1
// Symmetric fp8 MFMA miner (r10 structure — measured optimum): 256 thd =
// 2x2 waves, 128x128 tile, wave 64x64 via 4x4 frags of 16x16x32_fp8_fp8.
// Chunk K=64: one [128 rows][64 B] LDS panel per side; one ds_read_b128
// per row-tile covers both K=32 MFMAs (k-octets {2q,2q+1} — same
// permutation applied to A and B, so the dot is exact). Epilogue: u32
// keys, LDS merge (aliased over staging) + one atomicMax per row/side.
__global__ __launch_bounds__(256, 3) void mine_kernel(
    const unsigned char* __restrict__ q8, const int* __restrict__ tgt,
    const float* __restrict__ sqv,
    unsigned* __restrict__ pos_key, unsigned* __restrict__ neg_key)
{
    __shared__ __align__(16) unsigned Msh[2 * 128 * 33];  // merge; front 16KB = staging
    __shared__ float sqI[128], sqJ[128];
    __shared__ int   tgI[128], tgJ[128];
    char* const smem = (char*)Msh;                 // A: [0,8K), B: [8K,16K)

    // triangular tile map: blockIdx.x -> (bi, bj), bi <= bj
    int tt = blockIdx.x, bi = 0;
    while (tt >= NB - bi) { tt -= NB - bi; ++bi; }
    const int bj = bi + tt;
    const int i0 = bi * 128, j0 = bj * 128;
    const bool diag = (bi == bj);

    const int tid = threadIdx.x;
    const int w = tid >> 6, lane = tid & 63;
    const int quad = lane >> 4, lc = lane & 15;
    const int wy = w >> 1, wx = w & 1;

    if (tid < 128) { sqI[tid] = sqv[i0 + tid]; tgI[tid] = tgt[i0 + tid]; }
    else { const int c = tid - 128; sqJ[c] = sqv[j0 + c]; tgJ[c] = tgt[j0 + c]; }
    __syncthreads();  // acc-init reads sqI/sqJ

    // acc init: -(si + sqj)/2  =>  after MFMA chain, acc = -dist/2
    float sqjn[4];
    #pragma unroll
    for (int nt = 0; nt < 4; ++nt) sqjn[nt] = sqJ[wx * 64 + nt * 16 + lc];
    f32x4 acc[4][4];
    #pragma unroll
    for (int mt = 0; mt < 4; ++mt) {
        const f32x4 si4 = *(const f32x4*)&sqI[wy * 64 + mt * 16 + quad * 4];
        #pragma unroll
        for (int nt = 0; nt < 4; ++nt)
            #pragma unroll
            for (int r = 0; r < 4; ++r)
                acc[mt][nt][r] = -0.5f * (si4[r] + sqjn[nt]);
    }

    // K-loop: 4 chunks of K=64 (64 B/row fp8), panel = 512 16B slots
    for (int c = 0; c < D / 64; ++c) {
        const int dkb = c * 64;
        __syncthreads();                 // prev chunk's frag reads done
        #pragma unroll
        for (int it = 0; it < 2; ++it) {
            const int s = it * 256 + tid;         // slot id, 0..511
            const int r = s >> 2, bo = (s & 3) * 16;
            const int lbase = (it * 256 + w * 64) * 16;   // wave-uniform bytes
            gload16(q8 + (size_t)(i0 + r) * D + dkb + bo, smem + lbase);
            if (!diag)
                gload16(q8 + (size_t)(j0 + r) * D + dkb + bo, smem + 8192 + lbase);
        }
        __syncthreads();

        const char* AP = smem;
        const char* BP = diag ? AP : smem + 8192;
        union { int4 v; i64 d[2]; } fb[4], fa;
        #pragma unroll
        for (int t = 0; t < 4; ++t)
            fb[t].v = *(const int4*)(BP + (wx * 64 + t * 16 + lc) * 64 + quad * 16);
        #pragma unroll
        for (int mt = 0; mt < 4; ++mt) {
            fa.v = *(const int4*)(AP + (wy * 64 + mt * 16 + lc) * 64 + quad * 16);
            #pragma unroll
            for (int nt = 0; nt < 4; ++nt) {
                acc[mt][nt] = __builtin_amdgcn_mfma_f32_16x16x32_fp8_fp8(
                    fa.d[0], fb[nt].d[0], acc[mt][nt], 0, 0, 0);
                acc[mt][nt] = __builtin_amdgcn_mfma_f32_16x16x32_fp8_fp8(
                    fa.d[1], fb[nt].d[1], acc[mt][nt], 0, 0, 0);
            }
        }
    }
    __syncthreads();   // all frag reads done — staging LDS reusable as merge

    unsigned* const mpos = Msh;
    unsigned* const mneg = Msh + 128 * 33;

    // ---- epilogue: u32 keys, LDS-merge I-side, shuffle-merge J-side
    int tj[4]; unsigned jc[4], jpk[4], jnk[4];
    #pragma unroll
    for (int nt = 0; nt < 4; ++nt) {
        const int cl = wx * 64 + nt * 16 + lc;
        tj[nt] = tgJ[cl];
        jc[nt] = 0x1FFFu - (unsigned)(j0 + cl);   // I-side idx field (col)
        jpk[nt] = 0u; jnk[nt] = 0u;
    }

    #pragma unroll
    for (int mt = 0; mt < 4; ++mt) {
        const int rbase = wy * 64 + mt * 16 + quad * 4;
        const int4 ti4 = *(const int4*)&tgI[rbase];
        #pragma unroll
        for (int r = 0; r < 4; ++r) {
            const int sr = rbase + r;
            const unsigned rk = 0x1FFFu - (unsigned)(i0 + sr);  // J idx field
            const int ti = ((const int*)&ti4)[r];
            unsigned bpk = 0u, bnk = 0u;
            #pragma unroll
            for (int nt = 0; nt < 4; ++nt) {
                const int cl = wx * 64 + nt * 16 + lc;
                const float dist = fmaxf(-2.0f * acc[mt][nt][r], 0.0f);
                const unsigned db = __float_as_uint(dist) & 0xFFFFE000u;
                const bool same = (ti == tj[nt]);
                const bool dia = diag && (sr == cl);
                const unsigned pb_ = dia ? 0u : (same ? db : 0u);
                const unsigned nb_ = dia ? 0u : (same ? 0u : db);
                bpk = max(bpk, dia ? 0u : (pb_ | jc[nt]));
                bnk = max(bnk, dia ? 0u : (nb_ | jc[nt]));
                jpk[nt] = max(jpk[nt], dia ? 0u : (pb_ | rk));
                jnk[nt] = max(jnk[nt], dia ? 0u : (nb_ | rk));
            }
            mpos[sr * 33 + wx * 16 + lc] = bpk;
            mneg[sr * 33 + wx * 16 + lc] = bnk;
        }
    }
    __syncthreads();

    // I-side owner merge: tid<128 -> pos row tid; tid>=128 -> neg row tid-128
    {
        const int sr = tid & 127;
        const unsigned* m = (tid < 128) ? &mpos[sr * 33] : &mneg[sr * 33];
        unsigned best = 0u;
        #pragma unroll
        for (int k = 0; k < 32; ++k) best = max(best, m[k]);
        unsigned* gk = (tid < 128) ? pos_key : neg_key;
        atomicMax(&gk[i0 + sr], best);
    }

    // J-side: merge 4 quads within wave, then atomic (both wy waves emit)
    if (!diag) {
        #pragma unroll
        for (int nt = 0; nt < 4; ++nt) {
            unsigned pk = jpk[nt], nk = jnk[nt];
            #pragma unroll
            for (int off = 16; off < 64; off <<= 1) {
                pk = max(pk, (unsigned)__shfl_xor((int)pk, off, 64));
                nk = max(nk, (unsigned)__shfl_xor((int)nk, off, 64));
            }
            if (quad == 0) {
                const int gcol = j0 + wx * 64 + nt * 16 + lc;
                atomicMax(&pos_key[gcol], pk);
                atomicMax(&neg_key[gcol], nk);
            }
        }
    }
}

// ---------------------------------------------------------------- kernel 2
// Fused finalize + mean: decode indices, recompute exact fp32 distances,
// per-block partial sum, one atomicAdd per block (64 blocks -> no contention).
__global__ __launch_bounds__(256) void final_kernel(
    const float* __restrict__ q, const unsigned* __restrict__ pos_key,
    const unsigned* __restrict__ neg_key, float* __restrict__ out)
{
    __shared__ float red[4];
    const int wv = threadIdx.x >> 6, lane = threadIdx.x & 63;
    float wsum = 0.0f;
    for (int rr = 0; rr < 32; ++rr) {
        const int row = (blockIdx.x * 4 + wv) * 32 + rr;
        const int bpi = 0x1FFF - (int)(pos_key[row] & 0x1FFFu);
        const int bni = 0x1FFF - (int)(neg_key[row] & 0x1FFFu);
        const float4 qi = ((const float4*)(q + row * D))[lane];
        const float4 qp = ((const float4*)(q + (size_t)bpi * D))[lane];
        const float4 qn = ((const float4*)(q + (size_t)bni * D))[lane];
        float dx, dp = 0.0f, dn = 0.0f;
        dx = qi.x - qp.x; dp += dx * dx;
        dx = qi.y - qp.y; dp += dx * dx;
        dx = qi.z - qp.z; dp += dx * dx;
        dx = qi.w - qp.w; dp += dx * dx;
        dx = qi.x - qn.x; dn += dx * dx;
        dx = qi.y - qn.y; dn += dx * dx;
        dx = qi.z - qn.z; dn += dx * dx;
        dx = qi.w - qn.w; dn += dx * dx;
        #pragma unroll
        for (int off = 32; off; off >>= 1) {
            dp += __shfl_down(dp, off, 64);
            dn += __shfl_down(dn, off, 64);
        }
        if (lane == 0) wsum += fmaxf(0.0f, (1.0f - dp) + dn);
    }
    if (lane == 0) red[wv] = wsum;
    __syncthreads();
    if (threadIdx.x == 0)
        atomicAdd(out, (red[0] + red[1] + red[2] + red[3]) * (1.0f / N));
}

// ----------------------------------------------------------------
extern "C" void kernel_launch(void* const* d_in, const int* in_sizes, int n_in,
                              void* d_out, int out_size, void* d_ws, size_t ws_size,
                              hipStream_t stream) {
    const float* q = (const float*)d_in[0];
    const int* tgt = (const int*)d_in[1];
    float* out = (float*)d_out;

    // ws layout (~2.2 MB)
    unsigned* pos_key = (unsigned*)d_ws;              // N
    unsigned* neg_key = pos_key + N;                  // N
    unsigned char* q8 = (unsigned char*)(neg_key + N);// N*D bytes
    float* sqv = (float*)(q8 + (size_t)N * D);        // N

    prep_kernel<<<dim3(N / 4), dim3(256), 0, stream>>>(q, q8, sqv, pos_key, neg_key, out);
    mine_kernel<<<dim3(NTILES), dim3(256), 0, stream>>>(q8, tgt, sqv, pos_key, neg_key);
    final_kernel<<<dim3(64), dim3(256), 0, stream>>>(q, pos_key, neg_key, out);
}